// Round 13
// baseline (310.300 us; speedup 1.0000x reference)
//
#include <hip/hip_runtime.h>
#include <hip/hip_fp16.h>

#define N_IN_SZ   400000
#define N_OUT_SZ  200000
#define K_OFF     27
#define R_RULES   200000
#define NC        32

typedef unsigned int u32;
typedef __fp16 half2_t __attribute__((ext_vector_type(2)));

// ---------------- ws layouts ----------------
// Path A: f16 feat table (25.6 MB) + f16 accumulator (12.8 MB)
#define TAB_OFF      0ull
#define ACC_A_OFF    25600000ull
#define WS_A_NEEDED  (ACC_A_OFF + 12800000ull)     // 38,400,000
// Path B (R4): f16 accumulator at offset 0
#define ACC_WORDS    (N_OUT_SZ * 16)               // 3.2M half2
#define WS_B_NEEDED  ((size_t)ACC_WORDS * 4)       // 12.8 MB

__device__ __forceinline__ half2_t bc_h2(u32 w) {
    union { u32 u; half2_t v; } x; x.u = w; return x.v;
}

// ===========================================================================
// zero f16 accumulators (800K uint4)
// ===========================================================================
__global__ __launch_bounds__(256) void zero_acc_kernel(uint4* __restrict__ ws)
{
    const int total = ACC_WORDS / 4;
    int idx = blockIdx.x * 256 + threadIdx.x;
    if (idx < total) ws[idx] = make_uint4(0, 0, 0, 0);
}

// ===========================================================================
// feat f32 -> f16 table (rows become 64 B = ONE cache line per gather)
// ===========================================================================
__global__ __launch_bounds__(256) void convert_kernel(
    const float4* __restrict__ feat4, uint4* __restrict__ tab4)
{
    int t = blockIdx.x * 256 + threadIdx.x;        // 0 .. 1.6M
    if (t >= (N_IN_SZ * NC / 8)) return;
    float4 f0 = feat4[2 * t];
    float4 f1 = feat4[2 * t + 1];
    union { __half2 h; u32 u; } a, b, c, d;
    a.h = __floats2half2_rn(f0.x, f0.y);
    b.h = __floats2half2_rn(f0.z, f0.w);
    c.h = __floats2half2_rn(f1.x, f1.y);
    d.h = __floats2half2_rn(f1.z, f1.w);
    tab4[t] = make_uint4(a.u, b.u, c.u, d.u);
}

// ===========================================================================
// Path A conv: 16-lane group per rule; lane j = channels (2j, 2j+1).
// 4-DEEP pipeline: all 4 rules' feat rows (16 independent uint4 loads) issue
// before any compute. Weights packed half2, 32 VGPRs, k uniform per block.
// pk-f16 atomic scatter (fire-and-forget).
// ===========================================================================
#define LOADT(X0, X1, X2, X3, IR) { \
    const uint4* _p = reinterpret_cast<const uint4*>(tab + (size_t)(IR) * 16); \
    X0 = _p[0]; X1 = _p[1]; X2 = _p[2]; X3 = _p[3]; }

#if __has_builtin(__builtin_amdgcn_fdot2)
#define DOT2(ACC, FP, WP) ACC = __builtin_amdgcn_fdot2(bc_h2(FP), bc_h2(WP), ACC, false);
#else
#define DOT2(ACC, FP, WP) { \
    float2 _f = __half22float2(*(const __half2*)&(FP)); \
    float2 _w = __half22float2(*(const __half2*)&(WP)); \
    ACC += _f.x * _w.x + _f.y * _w.y; }
#endif

#define COMPQ(X, Q) { \
    DOT2(a0, X.x, w0[(Q)*4+0]); DOT2(a1, X.x, w1[(Q)*4+0]); \
    DOT2(a0, X.y, w0[(Q)*4+1]); DOT2(a1, X.y, w1[(Q)*4+1]); \
    DOT2(a0, X.z, w0[(Q)*4+2]); DOT2(a1, X.z, w1[(Q)*4+2]); \
    DOT2(a0, X.w, w0[(Q)*4+3]); DOT2(a1, X.w, w1[(Q)*4+3]); }

#define COMP(X0, X1, X2, X3, OD) { \
    float a0 = 0.f, a1 = 0.f; \
    COMPQ(X0, 0); COMPQ(X1, 1); COMPQ(X2, 2); COMPQ(X3, 3); \
    unsafeAtomicAdd(acc + (size_t)(OD) * 16 + j, __floats2half2_rn(a0, a1)); }

__global__ __launch_bounds__(256) void conv_a_kernel(
    const u32*   __restrict__ tab,      // [N_IN, 16] f16-pair dwords
    const float* __restrict__ weight,   // [27*32, 32] f32
    const int*   __restrict__ in_idx,   // [27, R]
    const int*   __restrict__ out_idx,  // [27, R]
    __half2*     __restrict__ acc)      // [N_OUT, 16]
{
    __shared__ u32 Wp[16 * 32];         // Wp[i2*32+c] = half2(w[2i2][c], w[2i2+1][c])
    const int k = blockIdx.y;
    for (int t = threadIdx.x; t < 512; t += 256) {
        const int i2 = t >> 5, c = t & 31;
        union { __half2 h; u32 u; } x;
        x.h = __floats2half2_rn(weight[(size_t)k * 1024 + (2 * i2) * 32 + c],
                                weight[(size_t)k * 1024 + (2 * i2 + 1) * 32 + c]);
        Wp[t] = x.u;
    }
    __syncthreads();

    const int j = threadIdx.x & 15;     // channel pair (2j, 2j+1)
    const int g = threadIdx.x >> 4;     // rule group 0..15

    u32 w0[16], w1[16];                 // 32 VGPRs, truly resident (k uniform)
#pragma unroll
    for (int i2 = 0; i2 < 16; ++i2) {
        w0[i2] = Wp[i2 * 32 + 2 * j];
        w1[i2] = Wp[i2 * 32 + 2 * j + 1];
    }

    const size_t base = (size_t)k * R_RULES + blockIdx.x * 64 + g;
    const int ir0 = in_idx[base],      ir1 = in_idx[base + 16];
    const int ir2 = in_idx[base + 32], ir3 = in_idx[base + 48];
    const int od0 = out_idx[base],      od1 = out_idx[base + 16];
    const int od2 = out_idx[base + 32], od3 = out_idx[base + 48];

    // ---- issue ALL 16 row loads (independent), then drain 4 computes ----
    uint4 A0, A1, A2, A3, B0, B1, B2, B3, C0, C1, C2, C3, D0, D1, D2, D3;
    LOADT(A0, A1, A2, A3, ir0);
    LOADT(B0, B1, B2, B3, ir1);
    LOADT(C0, C1, C2, C3, ir2);
    LOADT(D0, D1, D2, D3, ir3);

    COMP(A0, A1, A2, A3, od0);
    COMP(B0, B1, B2, B3, od1);
    COMP(C0, C1, C2, C3, od2);
    COMP(D0, D1, D2, D3, od3);
}

// ===========================================================================
// unpack: out[o][2j..2j+1] = float(acc) + bias
// ===========================================================================
__global__ __launch_bounds__(256) void unpack_kernel(
    const __half2* __restrict__ acc, const float* __restrict__ bias,
    float* __restrict__ out)
{
    int t = blockIdx.x * 256 + threadIdx.x;
    if (t >= ACC_WORDS) return;
    const int j = t & 15;
    const float2 v = __half22float2(acc[t]);
    const float2 b = reinterpret_cast<const float2*>(bias)[j];
    float2 o; o.x = v.x + b.x; o.y = v.y + b.y;
    reinterpret_cast<float2*>(out)[t] = o;
}

// ===========================================================================
// Path B: verbatim R4 (proven 634 µs)
// ===========================================================================
__global__ __launch_bounds__(256) void conv_scatter_f16_kernel(
    const float* __restrict__ feat, const float* __restrict__ weight,
    const int* __restrict__ in_idx, const int* __restrict__ out_idx,
    __half2* __restrict__ acc)
{
    __shared__ float2 Wlds[NC * 16];
    const int k = blockIdx.y;
    const float2* wg = reinterpret_cast<const float2*>(weight + k * NC * NC);
    for (int t = threadIdx.x; t < NC * 16; t += 256)
        Wlds[t] = wg[t];
    __syncthreads();
    const int j = threadIdx.x & 15;
    const int g = threadIdx.x >> 4;
    float2 wcol[NC];
#pragma unroll
    for (int i = 0; i < NC; ++i) wcol[i] = Wlds[i * 16 + j];
    const int rbase = blockIdx.x * 64;
    for (int rr = g; rr < 64; rr += 16) {
        const int r = rbase + rr;
        const int irow = in_idx[(size_t)k * R_RULES + r];
        const int orow = out_idx[(size_t)k * R_RULES + r];
        const float4* fv = reinterpret_cast<const float4*>(feat + (size_t)irow * NC);
        float a0 = 0.0f, a1 = 0.0f;
#pragma unroll
        for (int i0 = 0; i0 < 8; ++i0) {
            const float4 f = fv[i0];
            a0 += f.x * wcol[i0*4+0].x;  a1 += f.x * wcol[i0*4+0].y;
            a0 += f.y * wcol[i0*4+1].x;  a1 += f.y * wcol[i0*4+1].y;
            a0 += f.z * wcol[i0*4+2].x;  a1 += f.z * wcol[i0*4+2].y;
            a0 += f.w * wcol[i0*4+3].x;  a1 += f.w * wcol[i0*4+3].y;
        }
        unsafeAtomicAdd(acc + (size_t)orow * 16 + j, __floats2half2_rn(a0, a1));
    }
}

// Path C fallback: R2 f32 atomics (no ws)
__global__ __launch_bounds__(256) void init_out_kernel(
    const float* __restrict__ bias, float* __restrict__ out)
{
    int idx = blockIdx.x * 256 + threadIdx.x;
    const int total4 = N_OUT_SZ * NC / 4;
    if (idx >= total4) return;
    int c0 = (idx * 4) & (NC - 1);
    float4 b;
    b.x = bias[c0+0]; b.y = bias[c0+1]; b.z = bias[c0+2]; b.w = bias[c0+3];
    reinterpret_cast<float4*>(out)[idx] = b;
}

__global__ __launch_bounds__(256) void conv_scatter_kernel(
    const float* __restrict__ feat, const float* __restrict__ weight,
    const int* __restrict__ in_idx, const int* __restrict__ out_idx,
    float* __restrict__ out)
{
    __shared__ float Wlds[NC * NC];
    const int k  = blockIdx.y;
    const int c  = threadIdx.x & (NC - 1);
    const int rg = threadIdx.x >> 5;
    for (int t = threadIdx.x; t < NC * NC; t += 256)
        Wlds[t] = weight[k * NC * NC + t];
    __syncthreads();
    float wcol[NC];
#pragma unroll
    for (int i = 0; i < NC; ++i) wcol[i] = Wlds[i * NC + c];
    const int rbase = blockIdx.x * 64;
    for (int rr = rg; rr < 64; rr += 8) {
        const int r = rbase + rr;
        const int irow = in_idx[(size_t)k * R_RULES + r];
        const int orow = out_idx[(size_t)k * R_RULES + r];
        const float4* fv = reinterpret_cast<const float4*>(feat + (size_t)irow * NC);
        float acc = 0.0f;
#pragma unroll
        for (int i0 = 0; i0 < 8; ++i0) {
            const float4 f = fv[i0];
            acc += f.x * wcol[i0*4+0];
            acc += f.y * wcol[i0*4+1];
            acc += f.z * wcol[i0*4+2];
            acc += f.w * wcol[i0*4+3];
        }
        atomicAdd(out + (size_t)orow * NC + c, acc);
    }
}

// ---------------------------------------------------------------------------
extern "C" void kernel_launch(void* const* d_in, const int* in_sizes, int n_in,
                              void* d_out, int out_size, void* d_ws, size_t ws_size,
                              hipStream_t stream)
{
    const float* feat    = (const float*)d_in[0];
    const float* weight  = (const float*)d_in[1];
    const float* bias    = (const float*)d_in[2];
    const int*   in_idx  = (const int*)d_in[3];
    const int*   out_idx = (const int*)d_in[4];
    float*       out     = (float*)d_out;

    if (ws_size >= WS_A_NEEDED) {
        u32*     tab = (u32*)((char*)d_ws + TAB_OFF);
        __half2* acc = (__half2*)((char*)d_ws + ACC_A_OFF);

        zero_acc_kernel<<<(ACC_WORDS / 4 + 255) / 256, 256, 0, stream>>>(
            (uint4*)((char*)d_ws + ACC_A_OFF));
        convert_kernel<<<(N_IN_SZ * NC / 8 + 255) / 256, 256, 0, stream>>>(
            (const float4*)feat, (uint4*)tab);
        {
            dim3 grid(R_RULES / 64, K_OFF);
            conv_a_kernel<<<grid, 256, 0, stream>>>(tab, weight, in_idx, out_idx, acc);
        }
        unpack_kernel<<<ACC_WORDS / 256, 256, 0, stream>>>(acc, bias, out);
    } else if (ws_size >= WS_B_NEEDED) {
        __half2* acc = (__half2*)d_ws;
        zero_acc_kernel<<<(ACC_WORDS / 4 + 255) / 256, 256, 0, stream>>>((uint4*)d_ws);
        dim3 grid(R_RULES / 64, K_OFF);
        conv_scatter_f16_kernel<<<grid, 256, 0, stream>>>(feat, weight, in_idx, out_idx, acc);
        unpack_kernel<<<ACC_WORDS / 256, 256, 0, stream>>>(acc, bias, out);
    } else {
        int total4 = N_OUT_SZ * NC / 4;
        init_out_kernel<<<(total4 + 255) / 256, 256, 0, stream>>>(bias, out);
        dim3 grid(R_RULES / 64, K_OFF);
        conv_scatter_kernel<<<grid, 256, 0, stream>>>(feat, weight, in_idx, out_idx, out);
    }
}